// Round 13
// baseline (143.134 us; speedup 1.0000x reference)
//
#include <hip/hip_runtime.h>
#include <math.h>

#define ITERS 9
#define SIGMAF 0.1f

__device__ inline float rdl(float v, int l) {
    return __int_as_float(__builtin_amdgcn_readlane(__float_as_int(v), l));
}
template <int CTRL>
__device__ inline float dppf(float v) {
    return __int_as_float(__builtin_amdgcn_update_dpp(0, __float_as_int(v), CTRL, 0xF, 0xF, true));
}
__device__ inline float sum8_dpp(float p) {
    p += dppf<0xB1>(p);    // xor1
    p += dppf<0x4E>(p);    // xor2
    p += dppf<0x141>(p);   // row_half_mirror == xor4
    return p;
}
__device__ inline float wsum64_fast(float v) {
    v += dppf<0xB1>(v); v += dppf<0x4E>(v); v += dppf<0x141>(v);
    v += dppf<0x128>(v);   // row_ror:8
    return (rdl(v, 0) + rdl(v, 16)) + (rdl(v, 32) + rdl(v, 48));
}
__device__ inline float wmin64_fast(float v) {
    v = fminf(v, dppf<0xB1>(v)); v = fminf(v, dppf<0x4E>(v));
    v = fminf(v, dppf<0x141>(v)); v = fminf(v, dppf<0x128>(v));
    return fminf(fminf(rdl(v, 0), rdl(v, 16)), fminf(rdl(v, 32), rdl(v, 48)));
}

// Shallow 3x3 cofactor inverse (1 rcp, ~22cy depth). [R11-verified math]
__device__ inline void inv3u(const float p[3][3], float iv[3][3]) {
    float c00 = p[1][1]*p[2][2] - p[1][2]*p[2][1];
    float c01 = p[1][2]*p[2][0] - p[1][0]*p[2][2];
    float c02 = p[1][0]*p[2][1] - p[1][1]*p[2][0];
    float det = p[0][0]*c00 + p[0][1]*c01 + p[0][2]*c02;
    float di = __builtin_amdgcn_rcpf(det);
    iv[0][0] = c00*di;
    iv[1][0] = c01*di;
    iv[2][0] = c02*di;
    iv[0][1] = (p[0][2]*p[2][1]-p[0][1]*p[2][2])*di;
    iv[1][1] = (p[0][0]*p[2][2]-p[0][2]*p[2][0])*di;
    iv[2][1] = (p[0][1]*p[2][0]-p[0][0]*p[2][1])*di;
    iv[0][2] = (p[0][1]*p[1][2]-p[0][2]*p[1][1])*di;
    iv[1][2] = (p[0][2]*p[1][0]-p[0][0]*p[1][2])*di;
    iv[2][2] = (p[0][0]*p[1][1]-p[0][1]*p[1][0])*di;
}

// 3-row-block GJ level on [W | X | z] with fused Schur carry. [R11-verified]
__device__ inline void gjc3(float& w, float& x, float& z, float& bl,
                            float& wn, float& zn,
                            int r0, int g, int i, int g8) {
    float p[3][3], iv[3][3];
#pragma unroll
    for (int a = 0; a < 3; ++a)
#pragma unroll
        for (int b = 0; b < 3; ++b)
            p[a][b] = rdl(w, (r0 + a) * 8 + (r0 + b));
    float zs[3], rk[3], xk[3], m[3], mb[3];
#pragma unroll
    for (int a = 0; a < 3; ++a) {
        zs[a] = rdl(z, (r0 + a) * 8);
        rk[a] = __shfl(w, (r0 + a) * 8 + i);
        xk[a] = __shfl(x, (r0 + a) * 8 + i);
        m[a]  = __shfl(w, g8 + r0 + a);
        mb[a] = __shfl(bl, g8 + r0 + a);
    }
    inv3u(p, iv);
    float sr[3], sx[3], sz[3];
#pragma unroll
    for (int a = 0; a < 3; ++a) {
        sr[a] = iv[a][0]*rk[0] + iv[a][1]*rk[1] + iv[a][2]*rk[2];
        sx[a] = iv[a][0]*xk[0] + iv[a][1]*xk[1] + iv[a][2]*xk[2];
        sz[a] = iv[a][0]*zs[0] + iv[a][1]*zs[1] + iv[a][2]*zs[2];
    }
    bool q0 = (g == r0), q1 = (g == r0+1), q2 = (g == r0+2);
    float wu = w - (m[0]*sr[0] + m[1]*sr[1] + m[2]*sr[2]);
    float xu = x - (m[0]*sx[0] + m[1]*sx[1] + m[2]*sx[2]);
    float zu = z - (m[0]*sz[0] + m[1]*sz[1] + m[2]*sz[2]);
    w = q0 ? sr[0] : q1 ? sr[1] : q2 ? sr[2] : wu;
    x = q0 ? sx[0] : q1 ? sx[1] : q2 ? sx[2] : xu;
    z = q0 ? sz[0] : q1 ? sz[1] : q2 ? sz[2] : zu;
    bl -= mb[0]*sr[0] + mb[1]*sr[1] + mb[2]*sr[2];
    wn += mb[0]*sx[0] + mb[1]*sx[1] + mb[2]*sx[2];
    zn -= mb[0]*sz[0] + mb[1]*sz[1] + mb[2]*sz[2];
}
__device__ inline void gjz3(float& w, float& z, int r0, int g, int i, int g8) {
    float p[3][3], iv[3][3];
#pragma unroll
    for (int a = 0; a < 3; ++a)
#pragma unroll
        for (int b = 0; b < 3; ++b)
            p[a][b] = rdl(w, (r0 + a) * 8 + (r0 + b));
    float zs[3], rk[3], m[3];
#pragma unroll
    for (int a = 0; a < 3; ++a) {
        zs[a] = rdl(z, (r0 + a) * 8);
        rk[a] = __shfl(w, (r0 + a) * 8 + i);
        m[a]  = __shfl(w, g8 + r0 + a);
    }
    inv3u(p, iv);
    float sr[3], sz[3];
#pragma unroll
    for (int a = 0; a < 3; ++a) {
        sr[a] = iv[a][0]*rk[0] + iv[a][1]*rk[1] + iv[a][2]*rk[2];
        sz[a] = iv[a][0]*zs[0] + iv[a][1]*zs[1] + iv[a][2]*zs[2];
    }
    bool q0 = (g == r0), q1 = (g == r0+1), q2 = (g == r0+2);
    float wu = w - (m[0]*sr[0] + m[1]*sr[1] + m[2]*sr[2]);
    float zu = z - (m[0]*sz[0] + m[1]*sz[1] + m[2]*sz[2]);
    w = q0 ? sr[0] : q1 ? sr[1] : q2 ? sr[2] : wu;
    z = q0 ? sz[0] : q1 ? sz[1] : q2 ? sz[2] : zu;
}
// 2x2 level with fused carry. [R9-verified]
__device__ inline void gjc2(float& w, float& x, float& z, float& bl,
                            float& wn, float& zn,
                            int ra, int rb, int g, int i, int g8) {
    float p00 = rdl(w, ra * 9),      p01 = rdl(w, ra * 8 + rb);
    float p10 = rdl(w, rb * 8 + ra), p11 = rdl(w, rb * 9);
    float za  = rdl(z, ra * 8),      zbv = rdl(z, rb * 8);
    float rka = __shfl(w, ra * 8 + i), rkb = __shfl(w, rb * 8 + i);
    float xka = __shfl(x, ra * 8 + i), xkb = __shfl(x, rb * 8 + i);
    float ma  = __shfl(w, g8 + ra),    mb  = __shfl(w, g8 + rb);
    float mba = __shfl(bl, g8 + ra),   mbb = __shfl(bl, g8 + rb);
    float di = __builtin_amdgcn_rcpf(p00 * p11 - p01 * p10);
    float i00 = p11 * di, i01 = -p01 * di, i10 = -p10 * di, i11 = p00 * di;
    float sra = i00 * rka + i01 * rkb, srb = i10 * rka + i11 * rkb;
    float sxa = i00 * xka + i01 * xkb, sxb = i10 * xka + i11 * xkb;
    float sza = i00 * za  + i01 * zbv, szb = i10 * za  + i11 * zbv;
    bool pa = (g == ra), pb = (g == rb);
    w = pa ? sra : pb ? srb : w - ma * sra - mb * srb;
    x = pa ? sxa : pb ? sxb : x - ma * sxa - mb * sxb;
    z = pa ? sza : pb ? szb : z - ma * sza - mb * szb;
    bl -= mba * sra + mbb * srb;
    wn += mba * sxa + mbb * sxb;
    zn -= mba * sza + mbb * szb;
}
__device__ inline void gjz2(float& w, float& z, int ra, int rb,
                            int g, int i, int g8) {
    float p00 = rdl(w, ra * 9),      p01 = rdl(w, ra * 8 + rb);
    float p10 = rdl(w, rb * 8 + ra), p11 = rdl(w, rb * 9);
    float za  = rdl(z, ra * 8),      zbv = rdl(z, rb * 8);
    float rka = __shfl(w, ra * 8 + i), rkb = __shfl(w, rb * 8 + i);
    float ma  = __shfl(w, g8 + ra),    mb  = __shfl(w, g8 + rb);
    float di = __builtin_amdgcn_rcpf(p00 * p11 - p01 * p10);
    float i00 = p11 * di, i01 = -p01 * di, i10 = -p10 * di, i11 = p00 * di;
    float sra = i00 * rka + i01 * rkb, srb = i10 * rka + i11 * rkb;
    float sza = i00 * za + i01 * zbv,  szb = i10 * za + i11 * zbv;
    bool pa = (g == ra), pb = (g == rb);
    w = pa ? sra : pb ? srb : w - ma * sra - mb * srb;
    z = pa ? sza : pb ? szb : z - ma * sza - mb * szb;
}

// Cooperative 8x8 inverse via LDS (setup only).
__device__ void inv8_lds(const float (*src)[8], float (*dst)[8], float (*W)[16],
                         int r, int c) {
    W[r][c]     = src[r][c];
    W[r][c + 8] = (r == c) ? 1.0f : 0.0f;
    __syncthreads();
#pragma unroll
    for (int k = 0; k < 8; ++k) {
        float pinv = 1.0f / W[k][k];
        float m    = W[r][k];
        __syncthreads();
        if (r == k) { W[k][c] *= pinv; W[k][c + 8] *= pinv; }
        __syncthreads();
        float a0 = W[k][c], a1 = W[k][c + 8];
        if (r != k) { W[r][c] -= m * a0; W[r][c + 8] -= m * a1; }
        __syncthreads();
    }
    dst[r][c] = W[r][c + 8];
    __syncthreads();
}

extern "C" __global__ void __launch_bounds__(64, 1)
mpc_ipm_kernel(const float* __restrict__ x0g, const float* __restrict__ fg,
               const float* __restrict__ Ag, const float* __restrict__ Bg,
               const float* __restrict__ Cg, const float* __restrict__ Qg,
               const float* __restrict__ Rg, float* __restrict__ out)
{
    const int bi  = blockIdx.x;
    const int tid = threadIdx.x;
    const int g = tid >> 3, i = tid & 7;     // lane (g,i) = (row, col)
    const int isel = i & 4;
    const int pu = i & 3;
    const int g8 = g * 8;
    const int gp1 = ((g + 1) & 7) * 8, gm1 = ((g - 1) & 7) * 8;

    __shared__ float Amat[8][8], Bmat[8][4], Cmat[8][2], Qmat[8][8], Rmat[4][4];
    __shared__ float Qi[8][8], Vv[8][8], Uu[8][8];
    __shared__ float W[8][16];
    __shared__ float Rti[16][16];
    const float4* rti4 = reinterpret_cast<const float4*>(&Rti[0][0]);

    Amat[g][i] = Ag[tid];
    Qmat[g][i] = Qg[tid];
    if (tid < 32) Bmat[tid >> 2][tid & 3] = Bg[tid];
    if (tid < 16) { Cmat[tid >> 1][tid & 1] = Cg[tid]; Rmat[tid >> 2][tid & 3] = Rg[tid]; }
    __syncthreads();

    inv8_lds(Qmat, Qi, W, g, i);
    {
        float a = 0.0f;
#pragma unroll
        for (int k = 0; k < 8; ++k) a += Amat[g][k] * Qi[k][i];
        Vv[g][i] = a;
    }
    __syncthreads();
    {
        float a = 0.0f;
#pragma unroll
        for (int k = 0; k < 8; ++k) a += Vv[g][k] * Amat[i][k];
        Uu[g][i] = a;
    }
    __syncthreads();

    float Qrow[8], Arow[8], AcolT[8], Qirow[8];
    float Brow[4], brow3[4], Rrow[4], BcolU[8];
#pragma unroll
    for (int k = 0; k < 8; ++k) {
        Qrow[k] = Qmat[i][k]; Arow[k] = Amat[i][k]; AcolT[k] = Amat[k][i];
        Qirow[k] = Qi[i][k];
        BcolU[k] = Bmat[k][pu];
    }
#pragma unroll
    for (int p = 0; p < 4; ++p) { Brow[p] = Bmat[i][p]; brow3[p] = Bmat[g][p]; Rrow[p] = Rmat[pu][p]; }
    float qi_rc = Qi[g][i], uu_rc = Uu[g][i];
    float vv = Vv[g][i];            // V[r][c]
    float vv_cr = Vv[i][g];         // V^T[r][c]
    float C0 = Cmat[i][0], C1 = Cmat[i][1];

    const float* fptr = fg + bi * 32;
    const float* x0p  = x0g + bi * 8;
    float ba = C0 * fptr[4 * g] + C1 * fptr[4 * g + 1];
    float bb = C0 * fptr[4 * g + 2] + C1 * fptr[4 * g + 3];
    if (g == 0) {
#pragma unroll
        for (int j = 0; j < 8; ++j) ba += Arow[j] * x0p[j];
    }

    float xa = 0.f, xb = 0.f, na = 0.f, nb = 0.f;
    float ur = 0.f;
    float s1r = 1.f, s2r = 1.f, l1r = 1.f, l2r = 1.f;
    float da = 0.f, db = 0.f;

#pragma unroll 1
    for (int it = 0; it < ITERS; ++it) {
        float mu = wsum64_fast(s1r * l1r + s2r * l2r) * (1.0f / 128.0f);
        float smu = SIGMAF * mu;

        // ---- P1 u-side ----
        float rdu = l1r - l2r;
#pragma unroll
        for (int q = 0; q < 4; ++q) rdu += Rrow[q] * __shfl(ur, g8 + isel + q);
#pragma unroll
        for (int j = 0; j < 8; ++j) {
            float va = __shfl(na, g8 + j), vb = __shfl(nb, g8 + j);
            rdu -= BcolU[j] * (isel ? vb : va);
        }
        float ri1v = ur + s1r - 1.f, ri2v = -ur + s2r - 1.f;
        float rc1v = s1r * l1r - smu, rc2v = s2r * l2r - smu;
        float is1 = __builtin_amdgcn_rcpf(s1r), is2 = __builtin_amdgcn_rcpf(s2r);
        float dd1r = l1r * is1, dd2r = l2r * is2;
        float w1 = (l1r * ri1v - rc1v) * is1, w2 = (l2r * ri2v - rc2v) * is2;
        float rur = -(rdu + w1 - w2);

        // ---- P1 x-side ----
        float rxa = na, rxb = nb;
        float rpa = xa - ba, rpb = xb - bb;
#pragma unroll
        for (int j = 0; j < 8; ++j) {
            float xaj  = __shfl(xa, g8 + j);
            float xbj  = __shfl(xb, g8 + j);
            float nbj  = __shfl(nb, g8 + j);
            float naj1 = __shfl(na, gp1 + j);
            float xbj1 = __shfl(xb, gm1 + j);
            rxa += Qrow[j] * xaj - AcolT[j] * nbj;
            rxb += Qrow[j] * xbj - ((g < 7) ? AcolT[j] * naj1 : 0.f);
            rpb -= Arow[j] * xaj;
            rpa -= (g > 0) ? Arow[j] * xbj1 : 0.f;
        }
#pragma unroll
        for (int p = 0; p < 4; ++p) {
            rpa -= Brow[p] * __shfl(ur, g8 + p);
            rpb -= Brow[p] * __shfl(ur, g8 + 4 + p);
        }
        rxa = -rxa; rxb = -rxb;

        // ---- P2: 16x 4x4 inverses -> Rti (LDS) ----
        __syncthreads();
        {
            int base = (tid >> 1) * 8 + (tid & 1) * 4;
            float Mx[4][4], Iv[4][4];
#pragma unroll
            for (int a = 0; a < 4; ++a)
#pragma unroll
                for (int b = 0; b < 4; ++b) { Mx[a][b] = Rmat[a][b]; Iv[a][b] = (a == b) ? 1.f : 0.f; }
#pragma unroll
            for (int a = 0; a < 4; ++a)
                Mx[a][a] += __shfl(dd1r, base + a) + __shfl(dd2r, base + a);
#pragma unroll
            for (int k = 0; k < 4; ++k) {
                float p = __builtin_amdgcn_rcpf(Mx[k][k]);
#pragma unroll
                for (int b = 0; b < 4; ++b) { Mx[k][b] *= p; Iv[k][b] *= p; }
#pragma unroll
                for (int a = 0; a < 4; ++a) {
                    if (a == k) continue;
                    float m_ = Mx[a][k];
#pragma unroll
                    for (int b = 0; b < 4; ++b) { Mx[a][b] -= m_ * Mx[k][b]; Iv[a][b] -= m_ * Iv[k][b]; }
                }
            }
            if (tid < 16) {
#pragma unroll
                for (int a = 0; a < 4; ++a)
#pragma unroll
                    for (int b = 0; b < 4; ++b) Rti[tid][a * 4 + b] = Iv[a][b];
            }
        }
        float qxa = 0.f, qxb = 0.f;
#pragma unroll
        for (int j = 0; j < 8; ++j) {
            qxa += Qirow[j] * __shfl(rxa, g8 + j);
            qxb += Qirow[j] * __shfl(rxb, g8 + j);
        }
        __syncthreads();

        // ---- P3: qu + Dt blocks ----
        float qur;
        {
            float4 rr = rti4[(2 * g + (isel ? 1 : 0)) * 4 + pu];
            qur = rr.x * __shfl(rur, g8 + isel)
                + rr.y * __shfl(rur, g8 + isel + 1)
                + rr.z * __shfl(rur, g8 + isel + 2)
                + rr.w * __shfl(rur, g8 + isel + 3);
        }
        float dt_all[16];
#pragma unroll
        for (int t = 0; t < 16; ++t) {
            float a = qi_rc + (t > 0 ? uu_rc : 0.f);
#pragma unroll
            for (int p = 0; p < 4; ++p) {
                float4 rp4 = rti4[t * 4 + p];
                a += brow3[p] * (rp4.x * Brow[0] + rp4.y * Brow[1]
                               + rp4.z * Brow[2] + rp4.w * Brow[3]);
            }
            dt_all[t] = a;
        }

        // ---- P4: g = Am q + r_p ----
        float ga_ = qxa + rpa, gb_ = qxb + rpb;
#pragma unroll
        for (int j = 0; j < 8; ++j) {
            ga_ -= (g > 0) ? Arow[j] * __shfl(qxb, gm1 + j) : 0.f;
            gb_ -= Arow[j] * __shfl(qxa, g8 + j);
        }
#pragma unroll
        for (int p = 0; p < 4; ++p) {
            ga_ -= Brow[p] * __shfl(qur, g8 + p);
            gb_ -= Brow[p] * __shfl(qur, g8 + 4 + p);
        }

        // ---- P5: dual-ended sweep, 3-3-2 pivots, fused Schur carry ----
        float grall[16];
#pragma unroll
        for (int t = 0; t < 16; ++t)
            grall[t] = (t & 1) ? __shfl(gb_, (t >> 1) * 8 + g)
                               : __shfl(ga_, (t >> 1) * 8 + g);   // row-rep

        float xf_all[8], zf_all[8], xb_all[7], zb_all[7];
        float wf = dt_all[0], zf = grall[0];
        float wb = dt_all[15], zb = grall[15];
#pragma unroll
        for (int s = 0; s < 7; ++s) {
            float xf = vv_cr, blf = -vv;
            float xbk = vv,  blb = -vv_cr;
            float wnf = dt_all[s + 1],  znf = grall[s + 1];
            float wnb = dt_all[14 - s], znb = grall[14 - s];
            gjc3(wf, xf, zf, blf, wnf, znf, 0, g, i, g8);
            gjc3(wb, xbk, zb, blb, wnb, znb, 0, g, i, g8);
            gjc3(wf, xf, zf, blf, wnf, znf, 3, g, i, g8);
            gjc3(wb, xbk, zb, blb, wnb, znb, 3, g, i, g8);
            gjc2(wf, xf, zf, blf, wnf, znf, 6, 7, g, i, g8);
            gjc2(wb, xbk, zb, blb, wnb, znb, 6, 7, g, i, g8);
            xf_all[s] = xf; zf_all[s] = zf;
            xb_all[s] = xbk; zb_all[s] = zb;
            wf = wnf; zf = znf; wb = wnb; zb = znb;
        }
        // fwd stage 7 fused with junction: bottom block = (wb, zb) = (C~8, y~8)
        float x8c;
        {
            float xf = vv_cr, blf = -vv;
            float wnf = wb, znf = zb;
            gjc3(wf, xf, zf, blf, wnf, znf, 0, g, i, g8);
            gjc3(wf, xf, zf, blf, wnf, znf, 3, g, i, g8);
            gjc2(wf, xf, zf, blf, wnf, znf, 6, 7, g, i, g8);
            xf_all[7] = xf; zf_all[7] = zf;
            // junction solve: wnf x8 = znf
            gjz3(wnf, znf, 0, g, i, g8);
            gjz3(wnf, znf, 3, g, i, g8);
            gjz2(wnf, znf, 6, 7, g, i, g8);
            x8c = __shfl(znf, i * 8);          // row-rep -> col-rep
            da = (g == 4) ? x8c : da;          // dnu[8]
        }
        // ---- P6: dual outward back-substitution ----
        {
            float xcl = x8c, xcu = x8c;
#pragma unroll
            for (int j = 0; j < 8; ++j) {
                {
                    const int t = 7 - j;
                    float p = sum8_dpp(xf_all[t] * xcl);
                    float xr = zf_all[t] + p;
                    float xc = __shfl(xr, i * 8);
                    if (t & 1) db = (g == (t >> 1)) ? xc : db;
                    else       da = (g == (t >> 1)) ? xc : da;
                    xcl = xc;
                }
                if (j < 7) {
                    const int t = 9 + j;
                    float p = sum8_dpp(xb_all[6 - j] * xcu);
                    float xr = zb_all[6 - j] + p;
                    float xc = __shfl(xr, i * 8);
                    if (t & 1) db = (g == (t >> 1)) ? xc : db;
                    else       da = (g == (t >> 1)) ? xc : da;
                    xcu = xc;
                }
            }
        }

        // ---- P7: dz = M^-1 (rhs1 - Am' dnu) ----
        float hxa = rxa - da, hxb = rxb - db;
#pragma unroll
        for (int k = 0; k < 8; ++k) {
            hxa += AcolT[k] * __shfl(db, g8 + k);
            hxb += (g < 7) ? AcolT[k] * __shfl(da, gp1 + k) : 0.f;
        }
        float hur = rur;
#pragma unroll
        for (int k = 0; k < 8; ++k) {
            float va = __shfl(da, g8 + k), vb = __shfl(db, g8 + k);
            hur += BcolU[k] * (isel ? vb : va);
        }
        float dxa = 0.f, dxb = 0.f;
#pragma unroll
        for (int j = 0; j < 8; ++j) {
            dxa += Qirow[j] * __shfl(hxa, g8 + j);
            dxb += Qirow[j] * __shfl(hxb, g8 + j);
        }
        float dur;
        {
            float4 rr = rti4[(2 * g + (isel ? 1 : 0)) * 4 + pu];
            dur = rr.x * __shfl(hur, g8 + isel)
                + rr.y * __shfl(hur, g8 + isel + 1)
                + rr.z * __shfl(hur, g8 + isel + 2)
                + rr.w * __shfl(hur, g8 + isel + 3);
        }

        // ---- P8: ds, dlam, alpha, update ----
        float dss1 = -ri1v - dur;
        float dss2 = -ri2v + dur;
        float dll1 = (-rc1v - l1r * dss1) * is1;
        float dll2 = (-rc2v - l2r * dss2) * is2;
        float rmin = __builtin_inff();
        if (dss1 < 0.f) rmin = fminf(rmin, -s1r * __builtin_amdgcn_rcpf(dss1));
        if (dss2 < 0.f) rmin = fminf(rmin, -s2r * __builtin_amdgcn_rcpf(dss2));
        if (dll1 < 0.f) rmin = fminf(rmin, -l1r * __builtin_amdgcn_rcpf(dll1));
        if (dll2 < 0.f) rmin = fminf(rmin, -l2r * __builtin_amdgcn_rcpf(dll2));
        rmin = wmin64_fast(rmin);
        float alpha = fminf(1.f, 0.99f * rmin);

        ur  += alpha * dur;
        s1r += alpha * dss1; s2r += alpha * dss2;
        l1r += alpha * dll1; l2r += alpha * dll2;
        xa  += alpha * dxa;  xb  += alpha * dxb;
        na  += alpha * da;   nb  += alpha * db;
    }

    out[bi * 128 + 16 * g + i]     = xa;
    out[bi * 128 + 16 * g + 8 + i] = xb;
    out[16384 + bi * 64 + tid]     = ur;
}

extern "C" void kernel_launch(void* const* d_in, const int* in_sizes, int n_in,
                              void* d_out, int out_size, void* d_ws, size_t ws_size,
                              hipStream_t stream) {
    const float* x0 = (const float*)d_in[0];
    const float* fc = (const float*)d_in[1];
    const float* A  = (const float*)d_in[2];
    const float* B  = (const float*)d_in[3];
    const float* C  = (const float*)d_in[4];
    const float* Q  = (const float*)d_in[5];
    const float* R  = (const float*)d_in[6];
    float* out = (float*)d_out;
    const int batch = in_sizes[0] / 8;  // 128
    mpc_ipm_kernel<<<batch, 64, 0, stream>>>(x0, fc, A, B, C, Q, R, out);
}

// Round 14
// 100.235 us; speedup vs baseline: 1.4280x; 1.4280x over previous
//
#include <hip/hip_runtime.h>
#include <math.h>

#define ITERS 8
#define SIGMAF 0.1f

__device__ inline float rdl(float v, int l) {
    return __int_as_float(__builtin_amdgcn_readlane(__float_as_int(v), l));
}
template <int CTRL>
__device__ inline float dppf(float v) {
    return __int_as_float(__builtin_amdgcn_update_dpp(0, __float_as_int(v), CTRL, 0xF, 0xF, true));
}
__device__ inline float sum8_dpp(float p) {
    p += dppf<0xB1>(p);    // xor1
    p += dppf<0x4E>(p);    // xor2
    p += dppf<0x141>(p);   // row_half_mirror == xor4
    return p;
}
__device__ inline float wsum64_fast(float v) {
    v += dppf<0xB1>(v); v += dppf<0x4E>(v); v += dppf<0x141>(v);
    v += dppf<0x128>(v);   // row_ror:8
    return (rdl(v, 0) + rdl(v, 16)) + (rdl(v, 32) + rdl(v, 48));
}
__device__ inline float wmin64_fast(float v) {
    v = fminf(v, dppf<0xB1>(v)); v = fminf(v, dppf<0x4E>(v));
    v = fminf(v, dppf<0x141>(v)); v = fminf(v, dppf<0x128>(v));
    return fminf(fminf(rdl(v, 0), rdl(v, 16)), fminf(rdl(v, 32), rdl(v, 48)));
}

// One 2x2-block GJ level on augmented [W | X | z] WITH carried bottom block
// [bl | wn | zn] (Schur update fused — no separate combine round). [R9-verified]
__device__ inline void gjc(float& w, float& x, float& z, float& bl,
                           float& wn, float& zn,
                           int ra, int rb, int g, int i, int g8) {
    float p00 = rdl(w, ra * 9),      p01 = rdl(w, ra * 8 + rb);
    float p10 = rdl(w, rb * 8 + ra), p11 = rdl(w, rb * 9);
    float za  = rdl(z, ra * 8),      zbv = rdl(z, rb * 8);
    float rka = __shfl(w, ra * 8 + i), rkb = __shfl(w, rb * 8 + i);
    float xka = __shfl(x, ra * 8 + i), xkb = __shfl(x, rb * 8 + i);
    float ma  = __shfl(w, g8 + ra),    mb  = __shfl(w, g8 + rb);
    float mba = __shfl(bl, g8 + ra),   mbb = __shfl(bl, g8 + rb);
    float di = __builtin_amdgcn_rcpf(p00 * p11 - p01 * p10);
    float i00 = p11 * di, i01 = -p01 * di, i10 = -p10 * di, i11 = p00 * di;
    float sra = i00 * rka + i01 * rkb, srb = i10 * rka + i11 * rkb;
    float sxa = i00 * xka + i01 * xkb, sxb = i10 * xka + i11 * xkb;
    float sza = i00 * za  + i01 * zbv, szb = i10 * za  + i11 * zbv;
    bool pa = (g == ra), pb = (g == rb);
    w = pa ? sra : pb ? srb : w - ma * sra - mb * srb;
    x = pa ? sxa : pb ? sxb : x - ma * sxa - mb * sxb;
    z = pa ? sza : pb ? szb : z - ma * sza - mb * szb;
    bl -= mba * sra + mbb * srb;
    wn += mba * sxa + mbb * sxb;
    zn -= mba * sza + mbb * szb;
}
// z-only GJ level (junction solve)
__device__ inline void gjz(float& w, float& z, int ra, int rb,
                           int g, int i, int g8) {
    float p00 = rdl(w, ra * 9),      p01 = rdl(w, ra * 8 + rb);
    float p10 = rdl(w, rb * 8 + ra), p11 = rdl(w, rb * 9);
    float za  = rdl(z, ra * 8),      zbv = rdl(z, rb * 8);
    float rka = __shfl(w, ra * 8 + i), rkb = __shfl(w, rb * 8 + i);
    float ma  = __shfl(w, g8 + ra),    mb  = __shfl(w, g8 + rb);
    float di = __builtin_amdgcn_rcpf(p00 * p11 - p01 * p10);
    float i00 = p11 * di, i01 = -p01 * di, i10 = -p10 * di, i11 = p00 * di;
    float sra = i00 * rka + i01 * rkb, srb = i10 * rka + i11 * rkb;
    float sza = i00 * za + i01 * zbv,  szb = i10 * za + i11 * zbv;
    bool pa = (g == ra), pb = (g == rb);
    w = pa ? sra : pb ? srb : w - ma * sra - mb * srb;
    z = pa ? sza : pb ? szb : z - ma * sza - mb * szb;
}

// Cooperative 8x8 inverse via LDS (setup only).
__device__ void inv8_lds(const float (*src)[8], float (*dst)[8], float (*W)[16],
                         int r, int c) {
    W[r][c]     = src[r][c];
    W[r][c + 8] = (r == c) ? 1.0f : 0.0f;
    __syncthreads();
#pragma unroll
    for (int k = 0; k < 8; ++k) {
        float pinv = 1.0f / W[k][k];
        float m    = W[r][k];
        __syncthreads();
        if (r == k) { W[k][c] *= pinv; W[k][c + 8] *= pinv; }
        __syncthreads();
        float a0 = W[k][c], a1 = W[k][c + 8];
        if (r != k) { W[r][c] -= m * a0; W[r][c + 8] -= m * a1; }
        __syncthreads();
    }
    dst[r][c] = W[r][c + 8];
    __syncthreads();
}

extern "C" __global__ void __launch_bounds__(64, 1)
mpc_ipm_kernel(const float* __restrict__ x0g, const float* __restrict__ fg,
               const float* __restrict__ Ag, const float* __restrict__ Bg,
               const float* __restrict__ Cg, const float* __restrict__ Qg,
               const float* __restrict__ Rg, float* __restrict__ out)
{
    const int bi  = blockIdx.x;
    const int tid = threadIdx.x;
    const int g = tid >> 3, i = tid & 7;     // lane (g,i) = (row, col)
    const int isel = i & 4;
    const int pu = i & 3;
    const int g8 = g * 8;
    const int gp1 = ((g + 1) & 7) * 8, gm1 = ((g - 1) & 7) * 8;

    __shared__ float Amat[8][8], Bmat[8][4], Cmat[8][2], Qmat[8][8], Rmat[4][4];
    __shared__ float Qi[8][8], Vv[8][8], Uu[8][8];
    __shared__ float W[8][16];
    __shared__ float Rti[16][16];
    const float4* rti4 = reinterpret_cast<const float4*>(&Rti[0][0]);

    Amat[g][i] = Ag[tid];
    Qmat[g][i] = Qg[tid];
    if (tid < 32) Bmat[tid >> 2][tid & 3] = Bg[tid];
    if (tid < 16) { Cmat[tid >> 1][tid & 1] = Cg[tid]; Rmat[tid >> 2][tid & 3] = Rg[tid]; }
    __syncthreads();

    inv8_lds(Qmat, Qi, W, g, i);
    {
        float a = 0.0f;
#pragma unroll
        for (int k = 0; k < 8; ++k) a += Amat[g][k] * Qi[k][i];
        Vv[g][i] = a;
    }
    __syncthreads();
    {
        float a = 0.0f;
#pragma unroll
        for (int k = 0; k < 8; ++k) a += Vv[g][k] * Amat[i][k];
        Uu[g][i] = a;
    }
    __syncthreads();

    float Qrow[8], Arow[8], AcolT[8], Qirow[8];
    float Brow[4], brow3[4], Rrow[4], BcolU[8];
#pragma unroll
    for (int k = 0; k < 8; ++k) {
        Qrow[k] = Qmat[i][k]; Arow[k] = Amat[i][k]; AcolT[k] = Amat[k][i];
        Qirow[k] = Qi[i][k];
        BcolU[k] = Bmat[k][pu];
    }
#pragma unroll
    for (int p = 0; p < 4; ++p) { Brow[p] = Bmat[i][p]; brow3[p] = Bmat[g][p]; Rrow[p] = Rmat[pu][p]; }
    float qi_rc = Qi[g][i], uu_rc = Uu[g][i];
    float vv = Vv[g][i];            // V[r][c]
    float vv_cr = Vv[i][g];         // V^T[r][c]
    float C0 = Cmat[i][0], C1 = Cmat[i][1];

    const float* fptr = fg + bi * 32;
    const float* x0p  = x0g + bi * 8;
    float ba = C0 * fptr[4 * g] + C1 * fptr[4 * g + 1];
    float bb = C0 * fptr[4 * g + 2] + C1 * fptr[4 * g + 3];
    if (g == 0) {
#pragma unroll
        for (int j = 0; j < 8; ++j) ba += Arow[j] * x0p[j];
    }

    float xa = 0.f, xb = 0.f, na = 0.f, nb = 0.f;
    float ur = 0.f;
    float s1r = 1.f, s2r = 1.f, l1r = 1.f, l2r = 1.f;
    float da = 0.f, db = 0.f;

#pragma unroll 1
    for (int it = 0; it < ITERS; ++it) {
        float mu = wsum64_fast(s1r * l1r + s2r * l2r) * (1.0f / 128.0f);
        float smu = SIGMAF * mu;

        // ---- P1 u-side ----
        float rdu = l1r - l2r;
#pragma unroll
        for (int q = 0; q < 4; ++q) rdu += Rrow[q] * __shfl(ur, g8 + isel + q);
#pragma unroll
        for (int j = 0; j < 8; ++j) {
            float va = __shfl(na, g8 + j), vb = __shfl(nb, g8 + j);
            rdu -= BcolU[j] * (isel ? vb : va);
        }
        float ri1v = ur + s1r - 1.f, ri2v = -ur + s2r - 1.f;
        float rc1v = s1r * l1r - smu, rc2v = s2r * l2r - smu;
        float is1 = __builtin_amdgcn_rcpf(s1r), is2 = __builtin_amdgcn_rcpf(s2r);
        float dd1r = l1r * is1, dd2r = l2r * is2;
        float w1 = (l1r * ri1v - rc1v) * is1, w2 = (l2r * ri2v - rc2v) * is2;
        float rur = -(rdu + w1 - w2);

        // ---- P1 x-side ----
        float rxa = na, rxb = nb;
        float rpa = xa - ba, rpb = xb - bb;
#pragma unroll
        for (int j = 0; j < 8; ++j) {
            float xaj  = __shfl(xa, g8 + j);
            float xbj  = __shfl(xb, g8 + j);
            float nbj  = __shfl(nb, g8 + j);
            float naj1 = __shfl(na, gp1 + j);
            float xbj1 = __shfl(xb, gm1 + j);
            rxa += Qrow[j] * xaj - AcolT[j] * nbj;
            rxb += Qrow[j] * xbj - ((g < 7) ? AcolT[j] * naj1 : 0.f);
            rpb -= Arow[j] * xaj;
            rpa -= (g > 0) ? Arow[j] * xbj1 : 0.f;
        }
#pragma unroll
        for (int p = 0; p < 4; ++p) {
            rpa -= Brow[p] * __shfl(ur, g8 + p);
            rpb -= Brow[p] * __shfl(ur, g8 + 4 + p);
        }
        rxa = -rxa; rxb = -rxb;

        // ---- P2: 16x 4x4 inverses -> Rti (LDS) ----
        __syncthreads();
        {
            int base = (tid >> 1) * 8 + (tid & 1) * 4;
            float Mx[4][4], Iv[4][4];
#pragma unroll
            for (int a = 0; a < 4; ++a)
#pragma unroll
                for (int b = 0; b < 4; ++b) { Mx[a][b] = Rmat[a][b]; Iv[a][b] = (a == b) ? 1.f : 0.f; }
#pragma unroll
            for (int a = 0; a < 4; ++a)
                Mx[a][a] += __shfl(dd1r, base + a) + __shfl(dd2r, base + a);
#pragma unroll
            for (int k = 0; k < 4; ++k) {
                float p = __builtin_amdgcn_rcpf(Mx[k][k]);
#pragma unroll
                for (int b = 0; b < 4; ++b) { Mx[k][b] *= p; Iv[k][b] *= p; }
#pragma unroll
                for (int a = 0; a < 4; ++a) {
                    if (a == k) continue;
                    float m_ = Mx[a][k];
#pragma unroll
                    for (int b = 0; b < 4; ++b) { Mx[a][b] -= m_ * Mx[k][b]; Iv[a][b] -= m_ * Iv[k][b]; }
                }
            }
            if (tid < 16) {
#pragma unroll
                for (int a = 0; a < 4; ++a)
#pragma unroll
                    for (int b = 0; b < 4; ++b) Rti[tid][a * 4 + b] = Iv[a][b];
            }
        }
        float qxa = 0.f, qxb = 0.f;
#pragma unroll
        for (int j = 0; j < 8; ++j) {
            qxa += Qirow[j] * __shfl(rxa, g8 + j);
            qxb += Qirow[j] * __shfl(rxb, g8 + j);
        }
        __syncthreads();

        // ---- P3: qu + Dt blocks ----
        float qur;
        {
            float4 rr = rti4[(2 * g + (isel ? 1 : 0)) * 4 + pu];
            qur = rr.x * __shfl(rur, g8 + isel)
                + rr.y * __shfl(rur, g8 + isel + 1)
                + rr.z * __shfl(rur, g8 + isel + 2)
                + rr.w * __shfl(rur, g8 + isel + 3);
        }
        float dt_all[16];
#pragma unroll
        for (int t = 0; t < 16; ++t) {
            float a = qi_rc + (t > 0 ? uu_rc : 0.f);
#pragma unroll
            for (int p = 0; p < 4; ++p) {
                float4 rp4 = rti4[t * 4 + p];
                a += brow3[p] * (rp4.x * Brow[0] + rp4.y * Brow[1]
                               + rp4.z * Brow[2] + rp4.w * Brow[3]);
            }
            dt_all[t] = a;
        }

        // ---- P4: g = Am q + r_p ----
        float ga_ = qxa + rpa, gb_ = qxb + rpb;
#pragma unroll
        for (int j = 0; j < 8; ++j) {
            ga_ -= (g > 0) ? Arow[j] * __shfl(qxb, gm1 + j) : 0.f;
            gb_ -= Arow[j] * __shfl(qxa, g8 + j);
        }
#pragma unroll
        for (int p = 0; p < 4; ++p) {
            ga_ -= Brow[p] * __shfl(qur, g8 + p);
            gb_ -= Brow[p] * __shfl(qur, g8 + 4 + p);
        }

        // ---- P5: dual-ended sweep, 2x2-block GJ with FUSED Schur carry ----
        float grall[16];
#pragma unroll
        for (int t = 0; t < 16; ++t)
            grall[t] = (t & 1) ? __shfl(gb_, (t >> 1) * 8 + g)
                               : __shfl(ga_, (t >> 1) * 8 + g);   // row-rep

        float xf_all[8], zf_all[8], xb_all[7], zb_all[7];
        float wf = dt_all[0], zf = grall[0];
        float wb = dt_all[15], zb = grall[15];
#pragma unroll
        for (int s = 0; s < 7; ++s) {
            float xf = vv_cr, blf = -vv;
            float xbk = vv,  blb = -vv_cr;
            float wnf = dt_all[s + 1],  znf = grall[s + 1];
            float wnb = dt_all[14 - s], znb = grall[14 - s];
#pragma unroll
            for (int l = 0; l < 4; ++l) {
                gjc(wf, xf, zf, blf, wnf, znf, 2 * l, 2 * l + 1, g, i, g8);
                gjc(wb, xbk, zb, blb, wnb, znb, 2 * l, 2 * l + 1, g, i, g8);
            }
            xf_all[s] = xf; zf_all[s] = zf;
            xb_all[s] = xbk; zb_all[s] = zb;
            wf = wnf; zf = znf; wb = wnb; zb = znb;
        }
        // fwd stage 7 fused with junction: bottom block = (wb, zb) = (C~8, y~8)
        float x8c;
        {
            float xf = vv_cr, blf = -vv;
            float wnf = wb, znf = zb;
#pragma unroll
            for (int l = 0; l < 4; ++l)
                gjc(wf, xf, zf, blf, wnf, znf, 2 * l, 2 * l + 1, g, i, g8);
            xf_all[7] = xf; zf_all[7] = zf;
            // junction solve: wnf x8 = znf
#pragma unroll
            for (int l = 0; l < 4; ++l)
                gjz(wnf, znf, 2 * l, 2 * l + 1, g, i, g8);
            x8c = __shfl(znf, i * 8);          // row-rep -> col-rep
            da = (g == 4) ? x8c : da;          // dnu[8]
        }
        // ---- P6: dual outward back-substitution ----
        {
            float xcl = x8c, xcu = x8c;
#pragma unroll
            for (int j = 0; j < 8; ++j) {
                {
                    const int t = 7 - j;
                    float p = sum8_dpp(xf_all[t] * xcl);
                    float xr = zf_all[t] + p;
                    float xc = __shfl(xr, i * 8);
                    if (t & 1) db = (g == (t >> 1)) ? xc : db;
                    else       da = (g == (t >> 1)) ? xc : da;
                    xcl = xc;
                }
                if (j < 7) {
                    const int t = 9 + j;
                    float p = sum8_dpp(xb_all[6 - j] * xcu);
                    float xr = zb_all[6 - j] + p;
                    float xc = __shfl(xr, i * 8);
                    if (t & 1) db = (g == (t >> 1)) ? xc : db;
                    else       da = (g == (t >> 1)) ? xc : da;
                    xcu = xc;
                }
            }
        }

        // ---- P7: dz = M^-1 (rhs1 - Am' dnu) ----
        float hxa = rxa - da, hxb = rxb - db;
#pragma unroll
        for (int k = 0; k < 8; ++k) {
            hxa += AcolT[k] * __shfl(db, g8 + k);
            hxb += (g < 7) ? AcolT[k] * __shfl(da, gp1 + k) : 0.f;
        }
        float hur = rur;
#pragma unroll
        for (int k = 0; k < 8; ++k) {
            float va = __shfl(da, g8 + k), vb = __shfl(db, g8 + k);
            hur += BcolU[k] * (isel ? vb : va);
        }
        float dxa = 0.f, dxb = 0.f;
#pragma unroll
        for (int j = 0; j < 8; ++j) {
            dxa += Qirow[j] * __shfl(hxa, g8 + j);
            dxb += Qirow[j] * __shfl(hxb, g8 + j);
        }
        float dur;
        {
            float4 rr = rti4[(2 * g + (isel ? 1 : 0)) * 4 + pu];
            dur = rr.x * __shfl(hur, g8 + isel)
                + rr.y * __shfl(hur, g8 + isel + 1)
                + rr.z * __shfl(hur, g8 + isel + 2)
                + rr.w * __shfl(hur, g8 + isel + 3);
        }

        // ---- P8: ds, dlam, alpha, update ----
        float dss1 = -ri1v - dur;
        float dss2 = -ri2v + dur;
        float dll1 = (-rc1v - l1r * dss1) * is1;
        float dll2 = (-rc2v - l2r * dss2) * is2;
        float rmin = __builtin_inff();
        if (dss1 < 0.f) rmin = fminf(rmin, -s1r * __builtin_amdgcn_rcpf(dss1));
        if (dss2 < 0.f) rmin = fminf(rmin, -s2r * __builtin_amdgcn_rcpf(dss2));
        if (dll1 < 0.f) rmin = fminf(rmin, -l1r * __builtin_amdgcn_rcpf(dll1));
        if (dll2 < 0.f) rmin = fminf(rmin, -l2r * __builtin_amdgcn_rcpf(dll2));
        rmin = wmin64_fast(rmin);
        float alpha = fminf(1.f, 0.99f * rmin);

        ur  += alpha * dur;
        s1r += alpha * dss1; s2r += alpha * dss2;
        l1r += alpha * dll1; l2r += alpha * dll2;
        xa  += alpha * dxa;  xb  += alpha * dxb;
        na  += alpha * da;   nb  += alpha * db;
    }

    out[bi * 128 + 16 * g + i]     = xa;
    out[bi * 128 + 16 * g + 8 + i] = xb;
    out[16384 + bi * 64 + tid]     = ur;
}

extern "C" void kernel_launch(void* const* d_in, const int* in_sizes, int n_in,
                              void* d_out, int out_size, void* d_ws, size_t ws_size,
                              hipStream_t stream) {
    const float* x0 = (const float*)d_in[0];
    const float* fc = (const float*)d_in[1];
    const float* A  = (const float*)d_in[2];
    const float* B  = (const float*)d_in[3];
    const float* C  = (const float*)d_in[4];
    const float* Q  = (const float*)d_in[5];
    const float* R  = (const float*)d_in[6];
    float* out = (float*)d_out;
    const int batch = in_sizes[0] / 8;  // 128
    mpc_ipm_kernel<<<batch, 64, 0, stream>>>(x0, fc, A, B, C, Q, R, out);
}

// Round 15
// 88.968 us; speedup vs baseline: 1.6088x; 1.1266x over previous
//
#include <hip/hip_runtime.h>
#include <math.h>

#define ITERS 7
#define SIGMAF 0.1f

__device__ inline float rdl(float v, int l) {
    return __int_as_float(__builtin_amdgcn_readlane(__float_as_int(v), l));
}
template <int CTRL>
__device__ inline float dppf(float v) {
    return __int_as_float(__builtin_amdgcn_update_dpp(0, __float_as_int(v), CTRL, 0xF, 0xF, true));
}
__device__ inline float sum8_dpp(float p) {
    p += dppf<0xB1>(p);    // xor1
    p += dppf<0x4E>(p);    // xor2
    p += dppf<0x141>(p);   // row_half_mirror == xor4
    return p;
}
__device__ inline float wsum64_fast(float v) {
    v += dppf<0xB1>(v); v += dppf<0x4E>(v); v += dppf<0x141>(v);
    v += dppf<0x128>(v);   // row_ror:8
    return (rdl(v, 0) + rdl(v, 16)) + (rdl(v, 32) + rdl(v, 48));
}
__device__ inline float wmin64_fast(float v) {
    v = fminf(v, dppf<0xB1>(v)); v = fminf(v, dppf<0x4E>(v));
    v = fminf(v, dppf<0x141>(v)); v = fminf(v, dppf<0x128>(v));
    return fminf(fminf(rdl(v, 0), rdl(v, 16)), fminf(rdl(v, 32), rdl(v, 48)));
}

// One 2x2-block GJ level on augmented [W | X | z] WITH carried bottom block
// [bl | wn | zn] (Schur update fused — no separate combine round). [R9-verified]
__device__ inline void gjc(float& w, float& x, float& z, float& bl,
                           float& wn, float& zn,
                           int ra, int rb, int g, int i, int g8) {
    float p00 = rdl(w, ra * 9),      p01 = rdl(w, ra * 8 + rb);
    float p10 = rdl(w, rb * 8 + ra), p11 = rdl(w, rb * 9);
    float za  = rdl(z, ra * 8),      zbv = rdl(z, rb * 8);
    float rka = __shfl(w, ra * 8 + i), rkb = __shfl(w, rb * 8 + i);
    float xka = __shfl(x, ra * 8 + i), xkb = __shfl(x, rb * 8 + i);
    float ma  = __shfl(w, g8 + ra),    mb  = __shfl(w, g8 + rb);
    float mba = __shfl(bl, g8 + ra),   mbb = __shfl(bl, g8 + rb);
    float di = __builtin_amdgcn_rcpf(p00 * p11 - p01 * p10);
    float i00 = p11 * di, i01 = -p01 * di, i10 = -p10 * di, i11 = p00 * di;
    float sra = i00 * rka + i01 * rkb, srb = i10 * rka + i11 * rkb;
    float sxa = i00 * xka + i01 * xkb, sxb = i10 * xka + i11 * xkb;
    float sza = i00 * za  + i01 * zbv, szb = i10 * za  + i11 * zbv;
    bool pa = (g == ra), pb = (g == rb);
    w = pa ? sra : pb ? srb : w - ma * sra - mb * srb;
    x = pa ? sxa : pb ? sxb : x - ma * sxa - mb * sxb;
    z = pa ? sza : pb ? szb : z - ma * sza - mb * szb;
    bl -= mba * sra + mbb * srb;
    wn += mba * sxa + mbb * sxb;
    zn -= mba * sza + mbb * szb;
}
// z-only GJ level (junction solve)
__device__ inline void gjz(float& w, float& z, int ra, int rb,
                           int g, int i, int g8) {
    float p00 = rdl(w, ra * 9),      p01 = rdl(w, ra * 8 + rb);
    float p10 = rdl(w, rb * 8 + ra), p11 = rdl(w, rb * 9);
    float za  = rdl(z, ra * 8),      zbv = rdl(z, rb * 8);
    float rka = __shfl(w, ra * 8 + i), rkb = __shfl(w, rb * 8 + i);
    float ma  = __shfl(w, g8 + ra),    mb  = __shfl(w, g8 + rb);
    float di = __builtin_amdgcn_rcpf(p00 * p11 - p01 * p10);
    float i00 = p11 * di, i01 = -p01 * di, i10 = -p10 * di, i11 = p00 * di;
    float sra = i00 * rka + i01 * rkb, srb = i10 * rka + i11 * rkb;
    float sza = i00 * za + i01 * zbv,  szb = i10 * za + i11 * zbv;
    bool pa = (g == ra), pb = (g == rb);
    w = pa ? sra : pb ? srb : w - ma * sra - mb * srb;
    z = pa ? sza : pb ? szb : z - ma * sza - mb * szb;
}

// Cooperative 8x8 inverse via LDS (setup only).
__device__ void inv8_lds(const float (*src)[8], float (*dst)[8], float (*W)[16],
                         int r, int c) {
    W[r][c]     = src[r][c];
    W[r][c + 8] = (r == c) ? 1.0f : 0.0f;
    __syncthreads();
#pragma unroll
    for (int k = 0; k < 8; ++k) {
        float pinv = 1.0f / W[k][k];
        float m    = W[r][k];
        __syncthreads();
        if (r == k) { W[k][c] *= pinv; W[k][c + 8] *= pinv; }
        __syncthreads();
        float a0 = W[k][c], a1 = W[k][c + 8];
        if (r != k) { W[r][c] -= m * a0; W[r][c + 8] -= m * a1; }
        __syncthreads();
    }
    dst[r][c] = W[r][c + 8];
    __syncthreads();
}

extern "C" __global__ void __launch_bounds__(64, 1)
mpc_ipm_kernel(const float* __restrict__ x0g, const float* __restrict__ fg,
               const float* __restrict__ Ag, const float* __restrict__ Bg,
               const float* __restrict__ Cg, const float* __restrict__ Qg,
               const float* __restrict__ Rg, float* __restrict__ out)
{
    const int bi  = blockIdx.x;
    const int tid = threadIdx.x;
    const int g = tid >> 3, i = tid & 7;     // lane (g,i) = (row, col)
    const int isel = i & 4;
    const int pu = i & 3;
    const int g8 = g * 8;
    const int gp1 = ((g + 1) & 7) * 8, gm1 = ((g - 1) & 7) * 8;

    __shared__ float Amat[8][8], Bmat[8][4], Cmat[8][2], Qmat[8][8], Rmat[4][4];
    __shared__ float Qi[8][8], Vv[8][8], Uu[8][8];
    __shared__ float W[8][16];
    __shared__ float Rti[16][16];
    const float4* rti4 = reinterpret_cast<const float4*>(&Rti[0][0]);

    Amat[g][i] = Ag[tid];
    Qmat[g][i] = Qg[tid];
    if (tid < 32) Bmat[tid >> 2][tid & 3] = Bg[tid];
    if (tid < 16) { Cmat[tid >> 1][tid & 1] = Cg[tid]; Rmat[tid >> 2][tid & 3] = Rg[tid]; }
    __syncthreads();

    inv8_lds(Qmat, Qi, W, g, i);
    {
        float a = 0.0f;
#pragma unroll
        for (int k = 0; k < 8; ++k) a += Amat[g][k] * Qi[k][i];
        Vv[g][i] = a;
    }
    __syncthreads();
    {
        float a = 0.0f;
#pragma unroll
        for (int k = 0; k < 8; ++k) a += Vv[g][k] * Amat[i][k];
        Uu[g][i] = a;
    }
    __syncthreads();

    float Qrow[8], Arow[8], AcolT[8], Qirow[8];
    float Brow[4], brow3[4], Rrow[4], BcolU[8];
#pragma unroll
    for (int k = 0; k < 8; ++k) {
        Qrow[k] = Qmat[i][k]; Arow[k] = Amat[i][k]; AcolT[k] = Amat[k][i];
        Qirow[k] = Qi[i][k];
        BcolU[k] = Bmat[k][pu];
    }
#pragma unroll
    for (int p = 0; p < 4; ++p) { Brow[p] = Bmat[i][p]; brow3[p] = Bmat[g][p]; Rrow[p] = Rmat[pu][p]; }
    float qi_rc = Qi[g][i], uu_rc = Uu[g][i];
    float vv = Vv[g][i];            // V[r][c]
    float vv_cr = Vv[i][g];         // V^T[r][c]
    float C0 = Cmat[i][0], C1 = Cmat[i][1];

    const float* fptr = fg + bi * 32;
    const float* x0p  = x0g + bi * 8;
    float ba = C0 * fptr[4 * g] + C1 * fptr[4 * g + 1];
    float bb = C0 * fptr[4 * g + 2] + C1 * fptr[4 * g + 3];
    if (g == 0) {
#pragma unroll
        for (int j = 0; j < 8; ++j) ba += Arow[j] * x0p[j];
    }

    float xa = 0.f, xb = 0.f, na = 0.f, nb = 0.f;
    float ur = 0.f;
    float s1r = 1.f, s2r = 1.f, l1r = 1.f, l2r = 1.f;
    float da = 0.f, db = 0.f;

#pragma unroll 1
    for (int it = 0; it < ITERS; ++it) {
        float mu = wsum64_fast(s1r * l1r + s2r * l2r) * (1.0f / 128.0f);
        float smu = SIGMAF * mu;

        // ---- P1 u-side ----
        float rdu = l1r - l2r;
#pragma unroll
        for (int q = 0; q < 4; ++q) rdu += Rrow[q] * __shfl(ur, g8 + isel + q);
#pragma unroll
        for (int j = 0; j < 8; ++j) {
            float va = __shfl(na, g8 + j), vb = __shfl(nb, g8 + j);
            rdu -= BcolU[j] * (isel ? vb : va);
        }
        float ri1v = ur + s1r - 1.f, ri2v = -ur + s2r - 1.f;
        float rc1v = s1r * l1r - smu, rc2v = s2r * l2r - smu;
        float is1 = __builtin_amdgcn_rcpf(s1r), is2 = __builtin_amdgcn_rcpf(s2r);
        float dd1r = l1r * is1, dd2r = l2r * is2;
        float w1 = (l1r * ri1v - rc1v) * is1, w2 = (l2r * ri2v - rc2v) * is2;
        float rur = -(rdu + w1 - w2);

        // ---- P1 x-side ----
        float rxa = na, rxb = nb;
        float rpa = xa - ba, rpb = xb - bb;
#pragma unroll
        for (int j = 0; j < 8; ++j) {
            float xaj  = __shfl(xa, g8 + j);
            float xbj  = __shfl(xb, g8 + j);
            float nbj  = __shfl(nb, g8 + j);
            float naj1 = __shfl(na, gp1 + j);
            float xbj1 = __shfl(xb, gm1 + j);
            rxa += Qrow[j] * xaj - AcolT[j] * nbj;
            rxb += Qrow[j] * xbj - ((g < 7) ? AcolT[j] * naj1 : 0.f);
            rpb -= Arow[j] * xaj;
            rpa -= (g > 0) ? Arow[j] * xbj1 : 0.f;
        }
#pragma unroll
        for (int p = 0; p < 4; ++p) {
            rpa -= Brow[p] * __shfl(ur, g8 + p);
            rpb -= Brow[p] * __shfl(ur, g8 + 4 + p);
        }
        rxa = -rxa; rxb = -rxb;

        // ---- P2: 16x 4x4 inverses -> Rti (LDS) ----
        __syncthreads();
        {
            int base = (tid >> 1) * 8 + (tid & 1) * 4;
            float Mx[4][4], Iv[4][4];
#pragma unroll
            for (int a = 0; a < 4; ++a)
#pragma unroll
                for (int b = 0; b < 4; ++b) { Mx[a][b] = Rmat[a][b]; Iv[a][b] = (a == b) ? 1.f : 0.f; }
#pragma unroll
            for (int a = 0; a < 4; ++a)
                Mx[a][a] += __shfl(dd1r, base + a) + __shfl(dd2r, base + a);
#pragma unroll
            for (int k = 0; k < 4; ++k) {
                float p = __builtin_amdgcn_rcpf(Mx[k][k]);
#pragma unroll
                for (int b = 0; b < 4; ++b) { Mx[k][b] *= p; Iv[k][b] *= p; }
#pragma unroll
                for (int a = 0; a < 4; ++a) {
                    if (a == k) continue;
                    float m_ = Mx[a][k];
#pragma unroll
                    for (int b = 0; b < 4; ++b) { Mx[a][b] -= m_ * Mx[k][b]; Iv[a][b] -= m_ * Iv[k][b]; }
                }
            }
            if (tid < 16) {
#pragma unroll
                for (int a = 0; a < 4; ++a)
#pragma unroll
                    for (int b = 0; b < 4; ++b) Rti[tid][a * 4 + b] = Iv[a][b];
            }
        }
        float qxa = 0.f, qxb = 0.f;
#pragma unroll
        for (int j = 0; j < 8; ++j) {
            qxa += Qirow[j] * __shfl(rxa, g8 + j);
            qxb += Qirow[j] * __shfl(rxb, g8 + j);
        }
        __syncthreads();

        // ---- P3: qu + Dt blocks ----
        float qur;
        {
            float4 rr = rti4[(2 * g + (isel ? 1 : 0)) * 4 + pu];
            qur = rr.x * __shfl(rur, g8 + isel)
                + rr.y * __shfl(rur, g8 + isel + 1)
                + rr.z * __shfl(rur, g8 + isel + 2)
                + rr.w * __shfl(rur, g8 + isel + 3);
        }
        float dt_all[16];
#pragma unroll
        for (int t = 0; t < 16; ++t) {
            float a = qi_rc + (t > 0 ? uu_rc : 0.f);
#pragma unroll
            for (int p = 0; p < 4; ++p) {
                float4 rp4 = rti4[t * 4 + p];
                a += brow3[p] * (rp4.x * Brow[0] + rp4.y * Brow[1]
                               + rp4.z * Brow[2] + rp4.w * Brow[3]);
            }
            dt_all[t] = a;
        }

        // ---- P4: g = Am q + r_p ----
        float ga_ = qxa + rpa, gb_ = qxb + rpb;
#pragma unroll
        for (int j = 0; j < 8; ++j) {
            ga_ -= (g > 0) ? Arow[j] * __shfl(qxb, gm1 + j) : 0.f;
            gb_ -= Arow[j] * __shfl(qxa, g8 + j);
        }
#pragma unroll
        for (int p = 0; p < 4; ++p) {
            ga_ -= Brow[p] * __shfl(qur, g8 + p);
            gb_ -= Brow[p] * __shfl(qur, g8 + 4 + p);
        }

        // ---- P5: dual-ended sweep, 2x2-block GJ with FUSED Schur carry ----
        float grall[16];
#pragma unroll
        for (int t = 0; t < 16; ++t)
            grall[t] = (t & 1) ? __shfl(gb_, (t >> 1) * 8 + g)
                               : __shfl(ga_, (t >> 1) * 8 + g);   // row-rep

        float xf_all[8], zf_all[8], xb_all[7], zb_all[7];
        float wf = dt_all[0], zf = grall[0];
        float wb = dt_all[15], zb = grall[15];
#pragma unroll
        for (int s = 0; s < 7; ++s) {
            float xf = vv_cr, blf = -vv;
            float xbk = vv,  blb = -vv_cr;
            float wnf = dt_all[s + 1],  znf = grall[s + 1];
            float wnb = dt_all[14 - s], znb = grall[14 - s];
#pragma unroll
            for (int l = 0; l < 4; ++l) {
                gjc(wf, xf, zf, blf, wnf, znf, 2 * l, 2 * l + 1, g, i, g8);
                gjc(wb, xbk, zb, blb, wnb, znb, 2 * l, 2 * l + 1, g, i, g8);
            }
            xf_all[s] = xf; zf_all[s] = zf;
            xb_all[s] = xbk; zb_all[s] = zb;
            wf = wnf; zf = znf; wb = wnb; zb = znb;
        }
        // fwd stage 7 fused with junction: bottom block = (wb, zb) = (C~8, y~8)
        float x8c;
        {
            float xf = vv_cr, blf = -vv;
            float wnf = wb, znf = zb;
#pragma unroll
            for (int l = 0; l < 4; ++l)
                gjc(wf, xf, zf, blf, wnf, znf, 2 * l, 2 * l + 1, g, i, g8);
            xf_all[7] = xf; zf_all[7] = zf;
            // junction solve: wnf x8 = znf
#pragma unroll
            for (int l = 0; l < 4; ++l)
                gjz(wnf, znf, 2 * l, 2 * l + 1, g, i, g8);
            x8c = __shfl(znf, i * 8);          // row-rep -> col-rep
            da = (g == 4) ? x8c : da;          // dnu[8]
        }
        // ---- P6: dual outward back-substitution ----
        {
            float xcl = x8c, xcu = x8c;
#pragma unroll
            for (int j = 0; j < 8; ++j) {
                {
                    const int t = 7 - j;
                    float p = sum8_dpp(xf_all[t] * xcl);
                    float xr = zf_all[t] + p;
                    float xc = __shfl(xr, i * 8);
                    if (t & 1) db = (g == (t >> 1)) ? xc : db;
                    else       da = (g == (t >> 1)) ? xc : da;
                    xcl = xc;
                }
                if (j < 7) {
                    const int t = 9 + j;
                    float p = sum8_dpp(xb_all[6 - j] * xcu);
                    float xr = zb_all[6 - j] + p;
                    float xc = __shfl(xr, i * 8);
                    if (t & 1) db = (g == (t >> 1)) ? xc : db;
                    else       da = (g == (t >> 1)) ? xc : da;
                    xcu = xc;
                }
            }
        }

        // ---- P7: dz = M^-1 (rhs1 - Am' dnu) ----
        float hxa = rxa - da, hxb = rxb - db;
#pragma unroll
        for (int k = 0; k < 8; ++k) {
            hxa += AcolT[k] * __shfl(db, g8 + k);
            hxb += (g < 7) ? AcolT[k] * __shfl(da, gp1 + k) : 0.f;
        }
        float hur = rur;
#pragma unroll
        for (int k = 0; k < 8; ++k) {
            float va = __shfl(da, g8 + k), vb = __shfl(db, g8 + k);
            hur += BcolU[k] * (isel ? vb : va);
        }
        float dxa = 0.f, dxb = 0.f;
#pragma unroll
        for (int j = 0; j < 8; ++j) {
            dxa += Qirow[j] * __shfl(hxa, g8 + j);
            dxb += Qirow[j] * __shfl(hxb, g8 + j);
        }
        float dur;
        {
            float4 rr = rti4[(2 * g + (isel ? 1 : 0)) * 4 + pu];
            dur = rr.x * __shfl(hur, g8 + isel)
                + rr.y * __shfl(hur, g8 + isel + 1)
                + rr.z * __shfl(hur, g8 + isel + 2)
                + rr.w * __shfl(hur, g8 + isel + 3);
        }

        // ---- P8: ds, dlam, alpha, update ----
        float dss1 = -ri1v - dur;
        float dss2 = -ri2v + dur;
        float dll1 = (-rc1v - l1r * dss1) * is1;
        float dll2 = (-rc2v - l2r * dss2) * is2;
        float rmin = __builtin_inff();
        if (dss1 < 0.f) rmin = fminf(rmin, -s1r * __builtin_amdgcn_rcpf(dss1));
        if (dss2 < 0.f) rmin = fminf(rmin, -s2r * __builtin_amdgcn_rcpf(dss2));
        if (dll1 < 0.f) rmin = fminf(rmin, -l1r * __builtin_amdgcn_rcpf(dll1));
        if (dll2 < 0.f) rmin = fminf(rmin, -l2r * __builtin_amdgcn_rcpf(dll2));
        rmin = wmin64_fast(rmin);
        float alpha = fminf(1.f, 0.99f * rmin);

        ur  += alpha * dur;
        s1r += alpha * dss1; s2r += alpha * dss2;
        l1r += alpha * dll1; l2r += alpha * dll2;
        xa  += alpha * dxa;  xb  += alpha * dxb;
        na  += alpha * da;   nb  += alpha * db;
    }

    out[bi * 128 + 16 * g + i]     = xa;
    out[bi * 128 + 16 * g + 8 + i] = xb;
    out[16384 + bi * 64 + tid]     = ur;
}

extern "C" void kernel_launch(void* const* d_in, const int* in_sizes, int n_in,
                              void* d_out, int out_size, void* d_ws, size_t ws_size,
                              hipStream_t stream) {
    const float* x0 = (const float*)d_in[0];
    const float* fc = (const float*)d_in[1];
    const float* A  = (const float*)d_in[2];
    const float* B  = (const float*)d_in[3];
    const float* C  = (const float*)d_in[4];
    const float* Q  = (const float*)d_in[5];
    const float* R  = (const float*)d_in[6];
    float* out = (float*)d_out;
    const int batch = in_sizes[0] / 8;  // 128
    mpc_ipm_kernel<<<batch, 64, 0, stream>>>(x0, fc, A, B, C, Q, R, out);
}

// Round 18
// 88.327 us; speedup vs baseline: 1.6205x; 1.0073x over previous
//
#include <hip/hip_runtime.h>
#include <math.h>

#define ITERS 7
#define SIGMAF 0.1f

__device__ inline float rdl(float v, int l) {
    return __int_as_float(__builtin_amdgcn_readlane(__float_as_int(v), l));
}
template <int CTRL>
__device__ inline float dppf(float v) {
    return __int_as_float(__builtin_amdgcn_update_dpp(0, __float_as_int(v), CTRL, 0xF, 0xF, true));
}
__device__ inline float sum8_dpp(float p) {
    p += dppf<0xB1>(p);    // xor1
    p += dppf<0x4E>(p);    // xor2
    p += dppf<0x141>(p);   // row_half_mirror == xor4
    return p;
}
__device__ inline float wsum64_fast(float v) {
    v += dppf<0xB1>(v); v += dppf<0x4E>(v); v += dppf<0x141>(v);
    v += dppf<0x128>(v);   // row_ror:8
    return (rdl(v, 0) + rdl(v, 16)) + (rdl(v, 32) + rdl(v, 48));
}
__device__ inline float wmin64_fast(float v) {
    v = fminf(v, dppf<0xB1>(v)); v = fminf(v, dppf<0x4E>(v));
    v = fminf(v, dppf<0x141>(v)); v = fminf(v, dppf<0x128>(v));
    return fminf(fminf(rdl(v, 0), rdl(v, 16)), fminf(rdl(v, 32), rdl(v, 48)));
}

// Register/shuffle 8x8 Gauss-Jordan inverse (single matrix). [R2-verified]
__device__ inline float inv8_reg(float w, int r, int c) {
    float ii = (r == c) ? 1.0f : 0.0f;
#pragma unroll
    for (int k = 0; k < 8; ++k) {
        float wkk = __shfl(w, k * 9);
        float m   = __shfl(w, r * 8 + k);
        float wkc = __shfl(w, k * 8 + c);
        float ikc = __shfl(ii, k * 8 + c);
        float pinv = __builtin_amdgcn_rcpf(wkk);
        float ws = wkc * pinv;
        float is_ = ikc * pinv;
        bool diag = (r == k);
        w  = diag ? ws  : (w  - m * ws);
        ii = diag ? is_ : (ii - m * is_);
    }
    return ii;
}

// One 2x2-block GJ level on augmented [W | X | z] WITH carried bottom block
// [bl | wn | zn] (Schur update fused). [R9-verified]
__device__ inline void gjc(float& w, float& x, float& z, float& bl,
                           float& wn, float& zn,
                           int ra, int rb, int g, int i, int g8) {
    float p00 = rdl(w, ra * 9),      p01 = rdl(w, ra * 8 + rb);
    float p10 = rdl(w, rb * 8 + ra), p11 = rdl(w, rb * 9);
    float za  = rdl(z, ra * 8),      zbv = rdl(z, rb * 8);
    float rka = __shfl(w, ra * 8 + i), rkb = __shfl(w, rb * 8 + i);
    float xka = __shfl(x, ra * 8 + i), xkb = __shfl(x, rb * 8 + i);
    float ma  = __shfl(w, g8 + ra),    mb  = __shfl(w, g8 + rb);
    float mba = __shfl(bl, g8 + ra),   mbb = __shfl(bl, g8 + rb);
    float di = __builtin_amdgcn_rcpf(p00 * p11 - p01 * p10);
    float i00 = p11 * di, i01 = -p01 * di, i10 = -p10 * di, i11 = p00 * di;
    float sra = i00 * rka + i01 * rkb, srb = i10 * rka + i11 * rkb;
    float sxa = i00 * xka + i01 * xkb, sxb = i10 * xka + i11 * xkb;
    float sza = i00 * za  + i01 * zbv, szb = i10 * za  + i11 * zbv;
    bool pa = (g == ra), pb = (g == rb);
    w = pa ? sra : pb ? srb : w - ma * sra - mb * srb;
    x = pa ? sxa : pb ? sxb : x - ma * sxa - mb * sxb;
    z = pa ? sza : pb ? szb : z - ma * sza - mb * szb;
    bl -= mba * sra + mbb * srb;
    wn += mba * sxa + mbb * sxb;
    zn -= mba * sza + mbb * szb;
}
// z-only GJ level (junction solve)
__device__ inline void gjz(float& w, float& z, int ra, int rb,
                           int g, int i, int g8) {
    float p00 = rdl(w, ra * 9),      p01 = rdl(w, ra * 8 + rb);
    float p10 = rdl(w, rb * 8 + ra), p11 = rdl(w, rb * 9);
    float za  = rdl(z, ra * 8),      zbv = rdl(z, rb * 8);
    float rka = __shfl(w, ra * 8 + i), rkb = __shfl(w, rb * 8 + i);
    float ma  = __shfl(w, g8 + ra),    mb  = __shfl(w, g8 + rb);
    float di = __builtin_amdgcn_rcpf(p00 * p11 - p01 * p10);
    float i00 = p11 * di, i01 = -p01 * di, i10 = -p10 * di, i11 = p00 * di;
    float sra = i00 * rka + i01 * rkb, srb = i10 * rka + i11 * rkb;
    float sza = i00 * za + i01 * zbv,  szb = i10 * za + i11 * zbv;
    bool pa = (g == ra), pb = (g == rb);
    w = pa ? sra : pb ? srb : w - ma * sra - mb * srb;
    z = pa ? sza : pb ? szb : z - ma * sza - mb * szb;
}

extern "C" __global__ void __launch_bounds__(64, 1)
mpc_ipm_kernel(const float* __restrict__ x0g, const float* __restrict__ fg,
               const float* __restrict__ Ag, const float* __restrict__ Bg,
               const float* __restrict__ Cg, const float* __restrict__ Qg,
               const float* __restrict__ Rg, float* __restrict__ out)
{
    const int bi  = blockIdx.x;
    const int tid = threadIdx.x;
    const int g = tid >> 3, i = tid & 7;     // lane (g,i) = (row, col)
    const int isel = i & 4;
    const int pu = i & 3;
    const int g8 = g * 8;
    const int gp1 = ((g + 1) & 7) * 8, gm1 = ((g - 1) & 7) * 8;

    __shared__ float Bmat[8][4], Cmat[8][2], Rmat[4][4];
    __shared__ float Rti[16][16];
    const float4* rti4 = reinterpret_cast<const float4*>(&Rti[0][0]);

    // ---- load constants: A,Q per-lane registers; B,C,R to LDS ----
    float areg = Ag[tid];    // A[g][i]
    float qreg = Qg[tid];    // Q[g][i]
    if (tid < 32) Bmat[tid >> 2][tid & 3] = Bg[tid];
    if (tid < 16) { Cmat[tid >> 1][tid & 1] = Cg[tid]; Rmat[tid >> 2][tid & 3] = Rg[tid]; }
    __syncthreads();

    // ---- Qi = Q^-1 (register GJ), Vv = A*Qi, Uu = Vv*A^T (shfl rounds) ----
    float qi = inv8_reg(qreg, g, i);        // Qi[g][i]
    float vv = 0.f;
#pragma unroll
    for (int k = 0; k < 8; ++k)
        vv += __shfl(areg, g8 + k) * __shfl(qi, k * 8 + i);   // Vv[g][i]
    float uu_rc = 0.f;
#pragma unroll
    for (int k = 0; k < 8; ++k)
        uu_rc += __shfl(vv, g8 + k) * __shfl(areg, i * 8 + k); // Uu[g][i]

    // ---- per-lane register caches (independent shfl rounds) ----
    float Qrow[8], Arow[8], AcolT[8], Qirow[8];
    float Brow[4], brow3[4], Rrow[4], BcolU[8];
#pragma unroll
    for (int k = 0; k < 8; ++k) {
        Qrow[k]  = __shfl(qreg, i * 8 + k);   // Q[i][k]
        Arow[k]  = __shfl(areg, i * 8 + k);   // A[i][k]
        AcolT[k] = __shfl(areg, k * 8 + i);   // A[k][i]
        Qirow[k] = __shfl(qi,   i * 8 + k);   // Qi[i][k]
        BcolU[k] = Bmat[k][pu];
    }
#pragma unroll
    for (int p = 0; p < 4; ++p) { Brow[p] = Bmat[i][p]; brow3[p] = Bmat[g][p]; Rrow[p] = Rmat[pu][p]; }
    float qi_rc = qi;
    float vv_cr = __shfl(vv, i * 8 + g);      // V^T[g][i] = V[i][g]
    float C0 = Cmat[i][0], C1 = Cmat[i][1];

    const float* fptr = fg + bi * 32;
    const float* x0p  = x0g + bi * 8;
    float ba = C0 * fptr[4 * g] + C1 * fptr[4 * g + 1];
    float bb = C0 * fptr[4 * g + 2] + C1 * fptr[4 * g + 3];
    if (g == 0) {
#pragma unroll
        for (int j = 0; j < 8; ++j) ba += Arow[j] * x0p[j];
    }

    float xa = 0.f, xb = 0.f, na = 0.f, nb = 0.f;
    float ur = 0.f;
    float s1r = 1.f, s2r = 1.f, l1r = 1.f, l2r = 1.f;
    float da = 0.f, db = 0.f;

#pragma unroll 1
    for (int it = 0; it < ITERS; ++it) {
        float mu = wsum64_fast(s1r * l1r + s2r * l2r) * (1.0f / 128.0f);
        float smu = SIGMAF * mu;

        // ---- P1 u-side ----
        float rdu = l1r - l2r;
#pragma unroll
        for (int q = 0; q < 4; ++q) rdu += Rrow[q] * __shfl(ur, g8 + isel + q);
#pragma unroll
        for (int j = 0; j < 8; ++j) {
            float va = __shfl(na, g8 + j), vb = __shfl(nb, g8 + j);
            rdu -= BcolU[j] * (isel ? vb : va);
        }
        float ri1v = ur + s1r - 1.f, ri2v = -ur + s2r - 1.f;
        float rc1v = s1r * l1r - smu, rc2v = s2r * l2r - smu;
        float is1 = __builtin_amdgcn_rcpf(s1r), is2 = __builtin_amdgcn_rcpf(s2r);
        float dd1r = l1r * is1, dd2r = l2r * is2;
        float w1 = (l1r * ri1v - rc1v) * is1, w2 = (l2r * ri2v - rc2v) * is2;
        float rur = -(rdu + w1 - w2);

        // ---- P1 x-side ----
        float rxa = na, rxb = nb;
        float rpa = xa - ba, rpb = xb - bb;
#pragma unroll
        for (int j = 0; j < 8; ++j) {
            float xaj  = __shfl(xa, g8 + j);
            float xbj  = __shfl(xb, g8 + j);
            float nbj  = __shfl(nb, g8 + j);
            float naj1 = __shfl(na, gp1 + j);
            float xbj1 = __shfl(xb, gm1 + j);
            rxa += Qrow[j] * xaj - AcolT[j] * nbj;
            rxb += Qrow[j] * xbj - ((g < 7) ? AcolT[j] * naj1 : 0.f);
            rpb -= Arow[j] * xaj;
            rpa -= (g > 0) ? Arow[j] * xbj1 : 0.f;
        }
#pragma unroll
        for (int p = 0; p < 4; ++p) {
            rpa -= Brow[p] * __shfl(ur, g8 + p);
            rpb -= Brow[p] * __shfl(ur, g8 + 4 + p);
        }
        rxa = -rxa; rxb = -rxb;

        // ---- P2: 16x 4x4 inverses -> Rti (LDS) ----
        __syncthreads();
        {
            int base = (tid >> 1) * 8 + (tid & 1) * 4;
            float Mx[4][4], Iv[4][4];
#pragma unroll
            for (int a = 0; a < 4; ++a)
#pragma unroll
                for (int b = 0; b < 4; ++b) { Mx[a][b] = Rmat[a][b]; Iv[a][b] = (a == b) ? 1.f : 0.f; }
#pragma unroll
            for (int a = 0; a < 4; ++a)
                Mx[a][a] += __shfl(dd1r, base + a) + __shfl(dd2r, base + a);
#pragma unroll
            for (int k = 0; k < 4; ++k) {
                float p = __builtin_amdgcn_rcpf(Mx[k][k]);
#pragma unroll
                for (int b = 0; b < 4; ++b) { Mx[k][b] *= p; Iv[k][b] *= p; }
#pragma unroll
                for (int a = 0; a < 4; ++a) {
                    if (a == k) continue;
                    float m_ = Mx[a][k];
#pragma unroll
                    for (int b = 0; b < 4; ++b) { Mx[a][b] -= m_ * Mx[k][b]; Iv[a][b] -= m_ * Iv[k][b]; }
                }
            }
            if (tid < 16) {
#pragma unroll
                for (int a = 0; a < 4; ++a)
#pragma unroll
                    for (int b = 0; b < 4; ++b) Rti[tid][a * 4 + b] = Iv[a][b];
            }
        }
        float qxa = 0.f, qxb = 0.f;
#pragma unroll
        for (int j = 0; j < 8; ++j) {
            qxa += Qirow[j] * __shfl(rxa, g8 + j);
            qxb += Qirow[j] * __shfl(rxb, g8 + j);
        }
        __syncthreads();

        // ---- P3: qu + Dt blocks ----
        float qur;
        {
            float4 rr = rti4[(2 * g + (isel ? 1 : 0)) * 4 + pu];
            qur = rr.x * __shfl(rur, g8 + isel)
                + rr.y * __shfl(rur, g8 + isel + 1)
                + rr.z * __shfl(rur, g8 + isel + 2)
                + rr.w * __shfl(rur, g8 + isel + 3);
        }
        float dt_all[16];
#pragma unroll
        for (int t = 0; t < 16; ++t) {
            float a = qi_rc + (t > 0 ? uu_rc : 0.f);
#pragma unroll
            for (int p = 0; p < 4; ++p) {
                float4 rp4 = rti4[t * 4 + p];
                a += brow3[p] * (rp4.x * Brow[0] + rp4.y * Brow[1]
                               + rp4.z * Brow[2] + rp4.w * Brow[3]);
            }
            dt_all[t] = a;
        }

        // ---- P4: g = Am q + r_p ----
        float ga_ = qxa + rpa, gb_ = qxb + rpb;
#pragma unroll
        for (int j = 0; j < 8; ++j) {
            ga_ -= (g > 0) ? Arow[j] * __shfl(qxb, gm1 + j) : 0.f;
            gb_ -= Arow[j] * __shfl(qxa, g8 + j);
        }
#pragma unroll
        for (int p = 0; p < 4; ++p) {
            ga_ -= Brow[p] * __shfl(qur, g8 + p);
            gb_ -= Brow[p] * __shfl(qur, g8 + 4 + p);
        }

        // ---- P5: dual-ended sweep, 2x2-block GJ with FUSED Schur carry ----
        float grall[16];
#pragma unroll
        for (int t = 0; t < 16; ++t)
            grall[t] = (t & 1) ? __shfl(gb_, (t >> 1) * 8 + g)
                               : __shfl(ga_, (t >> 1) * 8 + g);   // row-rep

        float xf_all[8], zf_all[8], xb_all[7], zb_all[7];
        float wf = dt_all[0], zf = grall[0];
        float wb = dt_all[15], zb = grall[15];
#pragma unroll
        for (int s = 0; s < 7; ++s) {
            float xf = vv_cr, blf = -vv;
            float xbk = vv,  blb = -vv_cr;
            float wnf = dt_all[s + 1],  znf = grall[s + 1];
            float wnb = dt_all[14 - s], znb = grall[14 - s];
#pragma unroll
            for (int l = 0; l < 4; ++l) {
                gjc(wf, xf, zf, blf, wnf, znf, 2 * l, 2 * l + 1, g, i, g8);
                gjc(wb, xbk, zb, blb, wnb, znb, 2 * l, 2 * l + 1, g, i, g8);
            }
            xf_all[s] = xf; zf_all[s] = zf;
            xb_all[s] = xbk; zb_all[s] = zb;
            wf = wnf; zf = znf; wb = wnb; zb = znb;
        }
        // fwd stage 7 fused with junction: bottom block = (wb, zb) = (C~8, y~8)
        float x8c;
        {
            float xf = vv_cr, blf = -vv;
            float wnf = wb, znf = zb;
#pragma unroll
            for (int l = 0; l < 4; ++l)
                gjc(wf, xf, zf, blf, wnf, znf, 2 * l, 2 * l + 1, g, i, g8);
            xf_all[7] = xf; zf_all[7] = zf;
            // junction solve: wnf x8 = znf
#pragma unroll
            for (int l = 0; l < 4; ++l)
                gjz(wnf, znf, 2 * l, 2 * l + 1, g, i, g8);
            x8c = __shfl(znf, i * 8);          // row-rep -> col-rep
            da = (g == 4) ? x8c : da;          // dnu[8]
        }
        // ---- P6: dual outward back-substitution ----
        {
            float xcl = x8c, xcu = x8c;
#pragma unroll
            for (int j = 0; j < 8; ++j) {
                {
                    const int t = 7 - j;
                    float p = sum8_dpp(xf_all[t] * xcl);
                    float xr = zf_all[t] + p;
                    float xc = __shfl(xr, i * 8);
                    if (t & 1) db = (g == (t >> 1)) ? xc : db;
                    else       da = (g == (t >> 1)) ? xc : da;
                    xcl = xc;
                }
                if (j < 7) {
                    const int t = 9 + j;
                    float p = sum8_dpp(xb_all[6 - j] * xcu);
                    float xr = zb_all[6 - j] + p;
                    float xc = __shfl(xr, i * 8);
                    if (t & 1) db = (g == (t >> 1)) ? xc : db;
                    else       da = (g == (t >> 1)) ? xc : da;
                    xcu = xc;
                }
            }
        }

        // ---- P7: dz = M^-1 (rhs1 - Am' dnu) ----
        float hxa = rxa - da, hxb = rxb - db;
#pragma unroll
        for (int k = 0; k < 8; ++k) {
            hxa += AcolT[k] * __shfl(db, g8 + k);
            hxb += (g < 7) ? AcolT[k] * __shfl(da, gp1 + k) : 0.f;
        }
        float hur = rur;
#pragma unroll
        for (int k = 0; k < 8; ++k) {
            float va = __shfl(da, g8 + k), vb = __shfl(db, g8 + k);
            hur += BcolU[k] * (isel ? vb : va);
        }
        float dxa = 0.f, dxb = 0.f;
#pragma unroll
        for (int j = 0; j < 8; ++j) {
            dxa += Qirow[j] * __shfl(hxa, g8 + j);
            dxb += Qirow[j] * __shfl(hxb, g8 + j);
        }
        float dur;
        {
            float4 rr = rti4[(2 * g + (isel ? 1 : 0)) * 4 + pu];
            dur = rr.x * __shfl(hur, g8 + isel)
                + rr.y * __shfl(hur, g8 + isel + 1)
                + rr.z * __shfl(hur, g8 + isel + 2)
                + rr.w * __shfl(hur, g8 + isel + 3);
        }

        // ---- P8: ds, dlam, alpha, update ----
        float dss1 = -ri1v - dur;
        float dss2 = -ri2v + dur;
        float dll1 = (-rc1v - l1r * dss1) * is1;
        float dll2 = (-rc2v - l2r * dss2) * is2;
        float rmin = __builtin_inff();
        if (dss1 < 0.f) rmin = fminf(rmin, -s1r * __builtin_amdgcn_rcpf(dss1));
        if (dss2 < 0.f) rmin = fminf(rmin, -s2r * __builtin_amdgcn_rcpf(dss2));
        if (dll1 < 0.f) rmin = fminf(rmin, -l1r * __builtin_amdgcn_rcpf(dll1));
        if (dll2 < 0.f) rmin = fminf(rmin, -l2r * __builtin_amdgcn_rcpf(dll2));
        rmin = wmin64_fast(rmin);
        float alpha = fminf(1.f, 0.99f * rmin);

        ur  += alpha * dur;
        s1r += alpha * dss1; s2r += alpha * dss2;
        l1r += alpha * dll1; l2r += alpha * dll2;
        xa  += alpha * dxa;  xb  += alpha * dxb;
        na  += alpha * da;   nb  += alpha * db;
    }

    out[bi * 128 + 16 * g + i]     = xa;
    out[bi * 128 + 16 * g + 8 + i] = xb;
    out[16384 + bi * 64 + tid]     = ur;
}

extern "C" void kernel_launch(void* const* d_in, const int* in_sizes, int n_in,
                              void* d_out, int out_size, void* d_ws, size_t ws_size,
                              hipStream_t stream) {
    const float* x0 = (const float*)d_in[0];
    const float* fc = (const float*)d_in[1];
    const float* A  = (const float*)d_in[2];
    const float* B  = (const float*)d_in[3];
    const float* C  = (const float*)d_in[4];
    const float* Q  = (const float*)d_in[5];
    const float* R  = (const float*)d_in[6];
    float* out = (float*)d_out;
    const int batch = in_sizes[0] / 8;  // 128
    mpc_ipm_kernel<<<batch, 64, 0, stream>>>(x0, fc, A, B, C, Q, R, out);
}